// Round 1
// baseline (212.522 us; speedup 1.0000x reference)
//
#include <hip/hip_runtime.h>

// MTTT attention, MI355X gfx950.
// B=8, N=1024, C=1024, H=16, d=64, INNER_ITR=4, INNER_LR=1.0
//
// Algebra: the inner GD loop only needs G=k^Tk/N, P=k^Tv/N, mk, mv:
//   W <- W + P - G*W - mk (x) b ;  b <- mv - mk*W   (old W,b on RHS)
// which is an exact rearrangement of the reference iteration.

#define SEQ    1024
#define NBATCH 8
#define DIMC   1024
#define NHEAD  16
#define HDIM   64
#define MROWS  8192      // NBATCH*SEQ
#define NQKV   3072

typedef __attribute__((ext_vector_type(8))) __bf16 bf16x8;
typedef __attribute__((ext_vector_type(4))) float  f32x4;

__device__ __forceinline__ unsigned short f2b(float f) {
  union { float f; unsigned int u; } v; v.f = f;
  unsigned int r = (v.u + 0x7FFFu + ((v.u >> 16) & 1u)) >> 16; // RNE
  return (unsigned short)r;
}
__device__ __forceinline__ float b2f(unsigned short u) {
  union { unsigned int u; float f; } v; v.u = ((unsigned int)u) << 16;
  return v.f;
}

// async global->LDS, 16B per lane; LDS dest = wave-uniform base + lane*16
__device__ __forceinline__ void load_lds16(const void* g, void* l) {
  __builtin_amdgcn_global_load_lds(
      (__attribute__((address_space(1))) void*)(void*)(g),
      (__attribute__((address_space(3))) void*)(l), 16, 0, 0);
}

// ---------------- fp32 -> bf16 convert (vectorized) ----------------
__global__ __launch_bounds__(256) void cvt_bf16(const float* __restrict__ in,
                                                unsigned short* __restrict__ out,
                                                int n4) {
  int i = blockIdx.x * 256 + threadIdx.x;
  if (i >= n4) return;
  float4 v = ((const float4*)in)[i];
  ushort4 o;
  o.x = f2b(v.x); o.y = f2b(v.y); o.z = f2b(v.z); o.w = f2b(v.w);
  ((ushort4*)out)[i] = o;
}

// ------------- fp32 (R x Cc) -> bf16 transposed (Cc x R) -------------
__global__ __launch_bounds__(256) void transpose_cvt(const float* __restrict__ in,
                                                     unsigned short* __restrict__ out,
                                                     int R, int Cc) {
  __shared__ unsigned short tile[32][33];
  int c0 = blockIdx.x * 32, r0 = blockIdx.y * 32;
  int tx = threadIdx.x, ty = threadIdx.y;
  for (int i = ty; i < 32; i += 8)
    tile[i][tx] = f2b(in[(size_t)(r0 + i) * Cc + c0 + tx]);
  __syncthreads();
  for (int i = ty; i < 32; i += 8)
    out[(size_t)(c0 + i) * R + r0 + tx] = tile[tx][i];
}

// ---------------- NT bf16 GEMM: C[m][n] = sum_k A[m][k]*BT[n][k] ----------------
// 128x128 tile, BK=32, 256 threads (4 waves, 2x2), 16x16x32 MFMA (m97 structure).
// store_f32=0: bf16 out; store_f32=1: fp32 out + bias[n].
__global__ __launch_bounds__(256) void gemm_nt(const unsigned short* __restrict__ A,
                                               const unsigned short* __restrict__ BT,
                                               void* __restrict__ Cout,
                                               const float* __restrict__ bias,
                                               int M, int N, int K, int store_f32) {
  __shared__ unsigned short As[128 * 32];
  __shared__ unsigned short Bs[128 * 32];
  const int tid = threadIdx.x;
  const int lane = tid & 63, wave = tid >> 6;
  const int m0 = blockIdx.y * 128, n0 = blockIdx.x * 128;
  const int wr = wave >> 1, wc = wave & 1;

  f32x4 acc[4][4];
#pragma unroll
  for (int i = 0; i < 4; ++i)
#pragma unroll
    for (int j = 0; j < 4; ++j) acc[i][j] = f32x4{0.f, 0.f, 0.f, 0.f};

  // staging: wave w stages local rows [w*32, w*32+32); lane -> row w*32+(l>>2), k (l&3)*8
  const int sr = wave * 32 + (lane >> 2);
  const int sk = (lane & 3) * 8;
  const unsigned short* Ag = A + (size_t)(m0 + sr) * K + sk;
  const unsigned short* Bg = BT + (size_t)(n0 + sr) * K + sk;
  unsigned short* Al = &As[wave * 32 * 32];
  unsigned short* Bl = &Bs[wave * 32 * 32];

  const int frow = lane & 15;
  const int fk = (lane >> 4) * 8;

  for (int kk = 0; kk < K; kk += 32) {
    load_lds16(Ag + kk, Al);
    load_lds16(Ag + kk + 16 * K, Al + 16 * 32);
    load_lds16(Bg + kk, Bl);
    load_lds16(Bg + kk + 16 * K, Bl + 16 * 32);
    __syncthreads();
    bf16x8 af[4], bq[4];
#pragma unroll
    for (int i = 0; i < 4; ++i)
      af[i] = *(const bf16x8*)&As[(wr * 64 + i * 16 + frow) * 32 + fk];
#pragma unroll
    for (int j = 0; j < 4; ++j)
      bq[j] = *(const bf16x8*)&Bs[(wc * 64 + j * 16 + frow) * 32 + fk];
#pragma unroll
    for (int i = 0; i < 4; ++i)
#pragma unroll
      for (int j = 0; j < 4; ++j)
        acc[i][j] = __builtin_amdgcn_mfma_f32_16x16x32_bf16(af[i], bq[j], acc[i][j], 0, 0, 0);
    __syncthreads();
  }

  const int crow = m0 + wr * 64 + ((lane >> 4) << 2);
  const int ccol = n0 + wc * 64 + frow;
  if (store_f32) {
    float* C = (float*)Cout;
#pragma unroll
    for (int j = 0; j < 4; ++j) {
      float bv = bias ? bias[ccol + j * 16] : 0.f;
#pragma unroll
      for (int i = 0; i < 4; ++i)
#pragma unroll
        for (int r = 0; r < 4; ++r)
          C[(size_t)(crow + i * 16 + r) * N + ccol + j * 16] = acc[i][j][r] + bv;
    }
  } else {
    unsigned short* C = (unsigned short*)Cout;
#pragma unroll
    for (int i = 0; i < 4; ++i)
#pragma unroll
      for (int j = 0; j < 4; ++j)
#pragma unroll
        for (int r = 0; r < 4; ++r)
          C[(size_t)(crow + i * 16 + r) * N + ccol + j * 16] = f2b(acc[i][j][r]);
  }
}

// ------------- k,v: qkv layout (m, 3C) -> per-head d-major [bh][d][N] -------------
__global__ __launch_bounds__(256) void transpose_kv(const unsigned short* __restrict__ qkvb,
                                                    unsigned short* __restrict__ kt,
                                                    unsigned short* __restrict__ vt) {
  __shared__ unsigned short tile[64][80];  // stride 160B: 16B-aligned rows
  const int nc = blockIdx.x * 64;
  const int bh = blockIdx.y;
  const int which = blockIdx.z;           // 0 -> k (col base C), 1 -> v (col base 2C)
  const int b = bh >> 4, h = bh & 15;
  const int tid = threadIdx.x;
  const unsigned short* src = qkvb + (size_t)(b * SEQ + nc) * NQKV + (which + 1) * DIMC + h * HDIM;
  for (int idx = tid; idx < 512; idx += 256) {
    int rr = idx >> 3, ss = (idx & 7) * 8;
    *(uint4*)&tile[rr][ss] = *(const uint4*)&src[(size_t)rr * NQKV + ss];
  }
  __syncthreads();
  unsigned short* dst = (which ? vt : kt) + (size_t)bh * HDIM * SEQ;
  for (int idx = tid; idx < 512; idx += 256) {
    int dd = idx >> 3, ns = (idx & 7) * 8;
    alignas(16) unsigned short tmp[8];
#pragma unroll
    for (int jj = 0; jj < 8; ++jj) tmp[jj] = tile[ns + jj][dd];
    *(uint4*)&dst[(size_t)dd * SEQ + nc + ns] = *(const uint4*)tmp;
  }
}

// ------------- per-(b,h): G,P via MFMA + mk,mv + 4 GD iters -> W^T (bf16), b -------------
__global__ __launch_bounds__(256) void stats_gd(const unsigned short* __restrict__ kt,
                                                const unsigned short* __restrict__ vt,
                                                unsigned short* __restrict__ Wtb,
                                                float* __restrict__ bvec) {
  __shared__ float Gs[64][68];
  __shared__ float Ps[64][68];
  __shared__ float Ws[64][68];
  __shared__ float mkp[4][64], mvp[4][64];
  __shared__ float mks[64], mvs[64], bs[64];

  const int bh = blockIdx.x;
  const int tid = threadIdx.x;
  const int lane = tid & 63, wave = tid >> 6;
  const unsigned short* kb = kt + (size_t)bh * HDIM * SEQ;
  const unsigned short* vb = vt + (size_t)bh * HDIM * SEQ;
  const int frow = lane & 15;
  const int fk = (lane >> 4) * 8;

  // G[i][j] = sum_n ktd[i][n]*ktd[j][n]; both operand frags read kt rows identically.
  f32x4 accG[4], accP[4];
#pragma unroll
  for (int j = 0; j < 4; ++j) {
    accG[j] = f32x4{0.f, 0.f, 0.f, 0.f};
    accP[j] = f32x4{0.f, 0.f, 0.f, 0.f};
  }
  for (int nb = 0; nb < SEQ; nb += 32) {
    bf16x8 af = *(const bf16x8*)&kb[(size_t)(wave * 16 + frow) * SEQ + nb + fk];  // i-tile = wave
    bf16x8 kf[4], vf[4];
#pragma unroll
    for (int j = 0; j < 4; ++j)
      kf[j] = *(const bf16x8*)&kb[(size_t)(j * 16 + frow) * SEQ + nb + fk];
#pragma unroll
    for (int j = 0; j < 4; ++j)
      vf[j] = *(const bf16x8*)&vb[(size_t)(j * 16 + frow) * SEQ + nb + fk];
#pragma unroll
    for (int j = 0; j < 4; ++j) {
      accG[j] = __builtin_amdgcn_mfma_f32_16x16x32_bf16(af, kf[j], accG[j], 0, 0, 0);
      accP[j] = __builtin_amdgcn_mfma_f32_16x16x32_bf16(af, vf[j], accP[j], 0, 0, 0);
    }
  }
  const float invN = 1.0f / (float)SEQ;
  const int orow = wave * 16 + (lane >> 4) * 4;
#pragma unroll
  for (int j = 0; j < 4; ++j)
#pragma unroll
    for (int r = 0; r < 4; ++r) {
      Gs[orow + r][j * 16 + frow] = accG[j][r] * invN;
      Ps[orow + r][j * 16 + frow] = accP[j][r] * invN;
    }

  // row means: thread (wave,lane): quarter-sums of row `lane`
  {
    float sk_ = 0.f, sv_ = 0.f;
    const unsigned short* kr = &kb[(size_t)lane * SEQ + wave * 256];
    const unsigned short* vr = &vb[(size_t)lane * SEQ + wave * 256];
    for (int nn = 0; nn < 256; nn += 8) {
      uint4 a = *(const uint4*)&kr[nn];
      uint4 c = *(const uint4*)&vr[nn];
      const unsigned short* pa = (const unsigned short*)&a;
      const unsigned short* pc = (const unsigned short*)&c;
#pragma unroll
      for (int jj = 0; jj < 8; ++jj) { sk_ += b2f(pa[jj]); sv_ += b2f(pc[jj]); }
    }
    mkp[wave][lane] = sk_;
    mvp[wave][lane] = sv_;
  }
  __syncthreads();

  const int r = tid >> 2;
  const int c0 = (tid & 3) * 16;
  if (tid < 64) {
    mks[tid] = (mkp[0][tid] + mkp[1][tid] + mkp[2][tid] + mkp[3][tid]) * invN;
    mvs[tid] = (mvp[0][tid] + mvp[1][tid] + mvp[2][tid] + mvp[3][tid]) * invN;
    bs[tid] = 0.f;
  }
#pragma unroll
  for (int c = 0; c < 16; ++c) Ws[r][c0 + c] = 0.f;
  __syncthreads();

  // 4 GD iterations:  Wn = W + P - G*W - mk (x) b ;  bn = mv - mk*W
  for (int it = 0; it < 4; ++it) {
    float wn[16];
#pragma unroll
    for (int c = 0; c < 16; ++c)
      wn[c] = Ws[r][c0 + c] + Ps[r][c0 + c] - mks[r] * bs[c0 + c];
    for (int j = 0; j < 64; ++j) {
      float g = Gs[r][j];
#pragma unroll
      for (int c = 0; c < 16; ++c) wn[c] -= g * Ws[j][c0 + c];
    }
    float bn = 0.f;
    if (tid < 64) {
      bn = mvs[tid];
      for (int j = 0; j < 64; ++j) bn -= mks[j] * Ws[j][tid];
    }
    __syncthreads();
#pragma unroll
    for (int c = 0; c < 16; ++c) Ws[r][c0 + c] = wn[c];
    if (tid < 64) bs[tid] = bn;
    __syncthreads();
  }

  // emit W^T as bf16 (Wtb[bh][dd][j] = W[j][dd]) and b as fp32
  unsigned short* wout = Wtb + (size_t)bh * HDIM * HDIM;
#pragma unroll
  for (int c = 0; c < 16; ++c)
    wout[(size_t)(c0 + c) * HDIM + r] = f2b(Ws[r][c0 + c]);
  if (tid < 64) bvec[(size_t)bh * HDIM + tid] = bs[tid];
}

// ------------- attn[m][h*64+dd] = sum_j q[m][j] W[j][dd] + b[dd] (bf16 out) -------------
__global__ __launch_bounds__(256) void attn_qw(const unsigned short* __restrict__ qkvb,
                                               const unsigned short* __restrict__ Wtb,
                                               const float* __restrict__ bvec,
                                               unsigned short* __restrict__ attnb) {
  const int h = blockIdx.y;
  const int m0 = blockIdx.x * 128;
  const int bh = ((m0 >> 10) << 4) + h;
  const int tid = threadIdx.x;
  const int lane = tid & 63, wave = tid >> 6;
  const int frow = lane & 15;
  const int fk = (lane >> 4) * 8;

  f32x4 acc[2][4];
#pragma unroll
  for (int j = 0; j < 4; ++j) {
    float bv = bvec[(size_t)bh * HDIM + j * 16 + frow];
    f32x4 t; t[0] = bv; t[1] = bv; t[2] = bv; t[3] = bv;
    acc[0][j] = t; acc[1][j] = t;
  }

  const unsigned short* qbase = qkvb + (size_t)(m0 + wave * 32) * NQKV + h * HDIM;
  const unsigned short* wbase = Wtb + (size_t)bh * HDIM * HDIM;
#pragma unroll
  for (int s = 0; s < 2; ++s) {
    bf16x8 af[2], wf[4];
#pragma unroll
    for (int i = 0; i < 2; ++i)
      af[i] = *(const bf16x8*)&qbase[(size_t)(i * 16 + frow) * NQKV + s * 32 + fk];
#pragma unroll
    for (int j = 0; j < 4; ++j)
      wf[j] = *(const bf16x8*)&wbase[(size_t)(j * 16 + frow) * HDIM + s * 32 + fk];
#pragma unroll
    for (int i = 0; i < 2; ++i)
#pragma unroll
      for (int j = 0; j < 4; ++j)
        acc[i][j] = __builtin_amdgcn_mfma_f32_16x16x32_bf16(af[i], wf[j], acc[i][j], 0, 0, 0);
  }

  const int orow = m0 + wave * 32 + (lane >> 4) * 4;
#pragma unroll
  for (int i = 0; i < 2; ++i)
#pragma unroll
    for (int j = 0; j < 4; ++j)
#pragma unroll
      for (int rr = 0; rr < 4; ++rr)
        attnb[(size_t)(orow + i * 16 + rr) * DIMC + h * HDIM + j * 16 + frow] = f2b(acc[i][j][rr]);
}

extern "C" void kernel_launch(void* const* d_in, const int* in_sizes, int n_in,
                              void* d_out, int out_size, void* d_ws, size_t ws_size,
                              hipStream_t stream) {
  const float* x      = (const float*)d_in[0];
  const float* w_qkv  = (const float*)d_in[1];
  const float* w_proj = (const float*)d_in[2];
  const float* b_proj = (const float*)d_in[3];

  // workspace layout (bytes)
  char* ws = (char*)d_ws;
  unsigned short* xb    = (unsigned short*)(ws + 0);          //  16,777,216
  unsigned short* wqT   = (unsigned short*)(ws + 16777216);   //   6,291,456
  unsigned short* wpT   = (unsigned short*)(ws + 23068672);   //   2,097,152
  unsigned short* qkvb  = (unsigned short*)(ws + 25165824);   //  50,331,648
  unsigned short* kt    = (unsigned short*)(ws + 75497472);   //  16,777,216
  unsigned short* vt    = (unsigned short*)(ws + 92274688);   //  16,777,216
  unsigned short* attnb = (unsigned short*)(ws + 109051904);  //  16,777,216
  unsigned short* Wtb   = (unsigned short*)(ws + 125829120);  //   1,048,576
  float*          bvec  = (float*)(ws + 126877696);           //      32,768
  if (ws_size < (size_t)126910464) return;  // clean fail if workspace too small

  cvt_bf16<<<8192, 256, 0, stream>>>(x, xb, MROWS * DIMC / 4);
  transpose_cvt<<<dim3(96, 32), dim3(32, 8), 0, stream>>>(w_qkv, wqT, 1024, 3072);
  transpose_cvt<<<dim3(32, 32), dim3(32, 8), 0, stream>>>(w_proj, wpT, 1024, 1024);
  gemm_nt<<<dim3(24, 64), 256, 0, stream>>>(xb, wqT, qkvb, nullptr, MROWS, NQKV, DIMC, 0);
  transpose_kv<<<dim3(16, 128, 2), 256, 0, stream>>>(qkvb, kt, vt);
  stats_gd<<<128, 256, 0, stream>>>(kt, vt, Wtb, bvec);
  attn_qw<<<dim3(64, 16), 256, 0, stream>>>(qkvb, Wtb, bvec, attnb);
  gemm_nt<<<dim3(8, 64), 256, 0, stream>>>(attnb, wpT, d_out, b_proj, MROWS, DIMC, DIMC, 1);
}

// Round 2
// 200.262 us; speedup vs baseline: 1.0612x; 1.0612x over previous
//
#include <hip/hip_runtime.h>

// MTTT attention, MI355X gfx950.
// B=8, N=1024, C=1024, H=16, d=64, INNER_ITR=4, INNER_LR=1.0
//
// Algebra: the inner GD loop only needs G=k^Tk/N, P=k^Tv/N, mk, mv:
//   W <- W + P - G*W - mk (x) b ;  b <- mv - mk*W   (old W,b on RHS)
// which is an exact rearrangement of the reference iteration.

#define SEQ    1024
#define NBATCH 8
#define DIMC   1024
#define NHEAD  16
#define HDIM   64
#define MROWS  8192      // NBATCH*SEQ
#define NQKV   3072

typedef __attribute__((ext_vector_type(8))) __bf16 bf16x8;
typedef __attribute__((ext_vector_type(4))) float  f32x4;

__device__ __forceinline__ unsigned short f2b(float f) {
  union { float f; unsigned int u; } v; v.f = f;
  unsigned int r = (v.u + 0x7FFFu + ((v.u >> 16) & 1u)) >> 16; // RNE
  return (unsigned short)r;
}
__device__ __forceinline__ float b2f(unsigned short u) {
  union { unsigned int u; float f; } v; v.u = ((unsigned int)u) << 16;
  return v.f;
}

// async global->LDS, 16B per lane; LDS dest = wave-uniform base + lane*16
__device__ __forceinline__ void load_lds16(const void* g, void* l) {
  __builtin_amdgcn_global_load_lds(
      (__attribute__((address_space(1))) void*)(void*)(g),
      (__attribute__((address_space(3))) void*)(l), 16, 0, 0);
}

#define WAITVM(n_) do {                                                    \
    if ((n_) == 0) asm volatile("s_waitcnt vmcnt(0)" ::: "memory");        \
    else if ((n_) == 3) asm volatile("s_waitcnt vmcnt(3)" ::: "memory");   \
    else if ((n_) == 4) asm volatile("s_waitcnt vmcnt(4)" ::: "memory");   \
    else if ((n_) == 6) asm volatile("s_waitcnt vmcnt(6)" ::: "memory");   \
    else asm volatile("s_waitcnt vmcnt(8)" ::: "memory");                  \
  } while (0)

// ---------------- fp32 -> bf16 convert (vectorized) ----------------
__global__ __launch_bounds__(256) void cvt_bf16(const float* __restrict__ in,
                                                unsigned short* __restrict__ out,
                                                int n4) {
  int i = blockIdx.x * 256 + threadIdx.x;
  if (i >= n4) return;
  float4 v = ((const float4*)in)[i];
  ushort4 o;
  o.x = f2b(v.x); o.y = f2b(v.y); o.z = f2b(v.z); o.w = f2b(v.w);
  ((ushort4*)out)[i] = o;
}

// ------------- fp32 (R x Cc) -> bf16 transposed (Cc x R) -------------
__global__ __launch_bounds__(256) void transpose_cvt(const float* __restrict__ in,
                                                     unsigned short* __restrict__ out,
                                                     int R, int Cc) {
  __shared__ unsigned short tile[32][33];
  int c0 = blockIdx.x * 32, r0 = blockIdx.y * 32;
  int tx = threadIdx.x, ty = threadIdx.y;
  for (int i = ty; i < 32; i += 8)
    tile[i][tx] = f2b(in[(size_t)(r0 + i) * Cc + c0 + tx]);
  __syncthreads();
  for (int i = ty; i < 32; i += 8)
    out[(size_t)(c0 + i) * R + r0 + tx] = tile[tx][i];
}

// =====================================================================
// Slab-pipelined NT bf16 GEMM (T2+T3+T4+T5), K fixed at 1024.
//   C[m][n] = sum_k A[m][k] * BT[n][k]  (+bias, fp32 out, if STORE_F32)
// Tile BM x 256, BK-slab = 32, 8 waves (2x4), ring of 4 slabs in LDS.
// Per-slab window: vmcnt(counted) -> s_barrier -> stage slab s+3 ->
//                  ds_read frags -> setprio(1) MFMA setprio(0).
// LDS swizzle: 16B chunk c stored at c ^ (row&3); global source
// pre-swizzled so global_load_lds' linear dest yields that layout.
// MFMA operands swapped (mfma(B,A)) so each thread's 4 acc regs are 4
// consecutive output COLUMNS -> packed ushort4/float4 epilogue stores.
// =====================================================================
template <int BM, int STORE_F32>
__global__ __launch_bounds__(512, 2) void gemm8(const unsigned short* __restrict__ A,
                                                const unsigned short* __restrict__ BT,
                                                void* __restrict__ Cout,
                                                const float* __restrict__ bias,
                                                int N, int NBN) {
  constexpr int MI = BM / 32;          // m-frags per wave
  constexpr int CA = BM / 128;         // gload_lds calls per A-slab
  constexpr int ABYTES = BM * 64;      // A slab bytes (BM x 32 x bf16)
  constexpr int SLAB = ABYTES + 16384; // + B slab (256 x 32 x bf16)
  constexpr int CALLS = CA + 2;        // gload_lds calls per slab
  constexpr int WSTEADY = 2 * CALLS;   // 2 slabs in flight
  constexpr int WTAIL = CALLS;         // 1 slab in flight

  extern __shared__ __align__(16) char lds[];

  const int tid = threadIdx.x;
  const int lane = tid & 63, wave = tid >> 6;
  const int wr = wave >> 2, wc = wave & 3;
  const int frow = lane & 15;
  const int g4 = lane >> 4;
  const int cswz = (g4 ^ (frow & 3)) * 16;   // swizzled 16B-chunk byte offset

  // XCD-aware bijective block swizzle (gridDim.x % 8 == 0)
  const int cpx = gridDim.x >> 3;
  const int wg = (blockIdx.x & 7) * cpx + (blockIdx.x >> 3);
  const int bm = wg / NBN, bn = wg % NBN;
  const size_t m0 = (size_t)bm * BM, n0 = (size_t)bn * 256;

  // staging source (per-thread, pre-swizzled chunk)
  const int srow = tid >> 2;
  const int schunk = ((tid & 3) ^ (srow & 3)) * 8;  // element offset
  const unsigned short* srcA = A + (m0 + srow) * 1024 + schunk;
  const unsigned short* srcB = BT + (n0 + srow) * 1024 + schunk;
  const int wslot = wave * 1024;

  // fragment LDS byte offsets within a slab
  int aoff[MI], boff[4];
#pragma unroll
  for (int i = 0; i < MI; ++i) aoff[i] = (wr * (BM / 2) + i * 16 + frow) * 64 + cswz;
#pragma unroll
  for (int j = 0; j < 4; ++j)  boff[j] = ABYTES + (wc * 64 + j * 16 + frow) * 64 + cswz;

  f32x4 acc[MI][4];
  if (STORE_F32) {
#pragma unroll
    for (int j = 0; j < 4; ++j) {
      float4 bv = *(const float4*)&bias[n0 + wc * 64 + j * 16 + g4 * 4];
      f32x4 t; t[0] = bv.x; t[1] = bv.y; t[2] = bv.z; t[3] = bv.w;
#pragma unroll
      for (int i = 0; i < MI; ++i) acc[i][j] = t;
    }
  } else {
#pragma unroll
    for (int i = 0; i < MI; ++i)
#pragma unroll
      for (int j = 0; j < 4; ++j) acc[i][j] = f32x4{0.f, 0.f, 0.f, 0.f};
  }

  auto stage = [&](int s) {
    const int slot = s & 3;
    char* aL = lds + slot * SLAB + wslot;
    char* bL = lds + slot * SLAB + ABYTES + wslot;
    const unsigned short* aS = srcA + s * 32;
    const unsigned short* bS = srcB + s * 32;
    load_lds16(aS, aL);
    if (CA == 2) load_lds16(aS + 131072, aL + 8192);
    load_lds16(bS, bL);
    load_lds16(bS + 131072, bL + 8192);
  };

#define GEMM8_WINDOW(s_, wn_, dostage_) do {                                   \
    WAITVM(wn_);                                                               \
    __builtin_amdgcn_s_barrier();                                              \
    asm volatile("" ::: "memory");                                             \
    if (dostage_) stage((s_) + 3);                                             \
    const char* sa = lds + ((s_) & 3) * SLAB;                                  \
    bf16x8 af[MI], bq[4];                                                      \
    _Pragma("unroll") for (int i = 0; i < MI; ++i)                             \
      af[i] = *(const bf16x8*)(sa + aoff[i]);                                  \
    _Pragma("unroll") for (int j = 0; j < 4; ++j)                              \
      bq[j] = *(const bf16x8*)(sa + boff[j]);                                  \
    __builtin_amdgcn_s_setprio(1);                                             \
    _Pragma("unroll") for (int i = 0; i < MI; ++i)                             \
    _Pragma("unroll") for (int j = 0; j < 4; ++j)                              \
      acc[i][j] = __builtin_amdgcn_mfma_f32_16x16x32_bf16(bq[j], af[i],        \
                                                          acc[i][j], 0, 0, 0); \
    __builtin_amdgcn_s_setprio(0);                                             \
  } while (0)

  // prologue: stage slabs 0,1,2 (prefetch depth 3)
  stage(0); stage(1); stage(2);
  // 32 slabs total (K=1024, 32 k per slab)
  for (int s = 0; s < 30; ++s) GEMM8_WINDOW(s, WSTEADY, s < 29);
  GEMM8_WINDOW(30, WTAIL, false);
  GEMM8_WINDOW(31, 0, false);
#undef GEMM8_WINDOW

  // epilogue: thread holds 4 consecutive output columns per acc frag
  const size_t mbase = m0 + wr * (BM / 2) + frow;
  const size_t nbase = n0 + wc * 64 + g4 * 4;
  if (STORE_F32) {
    float* C = (float*)Cout;
#pragma unroll
    for (int i = 0; i < MI; ++i)
#pragma unroll
      for (int j = 0; j < 4; ++j) {
        float4 o; o.x = acc[i][j][0]; o.y = acc[i][j][1];
        o.z = acc[i][j][2]; o.w = acc[i][j][3];
        *(float4*)&C[(mbase + i * 16) * N + nbase + j * 16] = o;
      }
  } else {
    unsigned short* C = (unsigned short*)Cout;
#pragma unroll
    for (int i = 0; i < MI; ++i)
#pragma unroll
      for (int j = 0; j < 4; ++j) {
        ushort4 o; o.x = f2b(acc[i][j][0]); o.y = f2b(acc[i][j][1]);
        o.z = f2b(acc[i][j][2]); o.w = f2b(acc[i][j][3]);
        *(ushort4*)&C[(mbase + i * 16) * N + nbase + j * 16] = o;
      }
  }
}

// ------------- k,v: qkv layout (m, 3C) -> per-head d-major [bh][d][N] -------------
__global__ __launch_bounds__(256) void transpose_kv(const unsigned short* __restrict__ qkvb,
                                                    unsigned short* __restrict__ kt,
                                                    unsigned short* __restrict__ vt) {
  __shared__ unsigned short tile[64][80];  // stride 160B: 16B-aligned rows
  const int nc = blockIdx.x * 64;
  const int bh = blockIdx.y;
  const int which = blockIdx.z;           // 0 -> k (col base C), 1 -> v (col base 2C)
  const int b = bh >> 4, h = bh & 15;
  const int tid = threadIdx.x;
  const unsigned short* src = qkvb + (size_t)(b * SEQ + nc) * NQKV + (which + 1) * DIMC + h * HDIM;
  for (int idx = tid; idx < 512; idx += 256) {
    int rr = idx >> 3, ss = (idx & 7) * 8;
    *(uint4*)&tile[rr][ss] = *(const uint4*)&src[(size_t)rr * NQKV + ss];
  }
  __syncthreads();
  unsigned short* dst = (which ? vt : kt) + (size_t)bh * HDIM * SEQ;
  for (int idx = tid; idx < 512; idx += 256) {
    int dd = idx >> 3, ns = (idx & 7) * 8;
    alignas(16) unsigned short tmp[8];
#pragma unroll
    for (int jj = 0; jj < 8; ++jj) tmp[jj] = tile[ns + jj][dd];
    *(uint4*)&dst[(size_t)dd * SEQ + nc + ns] = *(const uint4*)tmp;
  }
}

// ------------- per-(b,h): G,P via MFMA + mk,mv + 4 GD iters -> W^T (bf16), b -------------
__global__ __launch_bounds__(256) void stats_gd(const unsigned short* __restrict__ kt,
                                                const unsigned short* __restrict__ vt,
                                                unsigned short* __restrict__ Wtb,
                                                float* __restrict__ bvec) {
  __shared__ float Gs[64][68];
  __shared__ float Ps[64][68];
  __shared__ float Ws[64][68];
  __shared__ float mkp[4][64], mvp[4][64];
  __shared__ float mks[64], mvs[64], bs[64];

  const int bh = blockIdx.x;
  const int tid = threadIdx.x;
  const int lane = tid & 63, wave = tid >> 6;
  const unsigned short* kb = kt + (size_t)bh * HDIM * SEQ;
  const unsigned short* vb = vt + (size_t)bh * HDIM * SEQ;
  const int frow = lane & 15;
  const int fk = (lane >> 4) * 8;

  // G[i][j] = sum_n ktd[i][n]*ktd[j][n]; both operand frags read kt rows identically.
  f32x4 accG[4], accP[4];
#pragma unroll
  for (int j = 0; j < 4; ++j) {
    accG[j] = f32x4{0.f, 0.f, 0.f, 0.f};
    accP[j] = f32x4{0.f, 0.f, 0.f, 0.f};
  }
  for (int nb = 0; nb < SEQ; nb += 32) {
    bf16x8 af = *(const bf16x8*)&kb[(size_t)(wave * 16 + frow) * SEQ + nb + fk];  // i-tile = wave
    bf16x8 kf[4], vf[4];
#pragma unroll
    for (int j = 0; j < 4; ++j)
      kf[j] = *(const bf16x8*)&kb[(size_t)(j * 16 + frow) * SEQ + nb + fk];
#pragma unroll
    for (int j = 0; j < 4; ++j)
      vf[j] = *(const bf16x8*)&vb[(size_t)(j * 16 + frow) * SEQ + nb + fk];
#pragma unroll
    for (int j = 0; j < 4; ++j) {
      accG[j] = __builtin_amdgcn_mfma_f32_16x16x32_bf16(af, kf[j], accG[j], 0, 0, 0);
      accP[j] = __builtin_amdgcn_mfma_f32_16x16x32_bf16(af, vf[j], accP[j], 0, 0, 0);
    }
  }
  const float invN = 1.0f / (float)SEQ;
  const int orow = wave * 16 + (lane >> 4) * 4;
#pragma unroll
  for (int j = 0; j < 4; ++j)
#pragma unroll
    for (int r = 0; r < 4; ++r) {
      Gs[orow + r][j * 16 + frow] = accG[j][r] * invN;
      Ps[orow + r][j * 16 + frow] = accP[j][r] * invN;
    }

  // row means: thread (wave,lane): quarter-sums of row `lane`
  {
    float sk_ = 0.f, sv_ = 0.f;
    const unsigned short* kr = &kb[(size_t)lane * SEQ + wave * 256];
    const unsigned short* vr = &vb[(size_t)lane * SEQ + wave * 256];
    for (int nn = 0; nn < 256; nn += 8) {
      uint4 a = *(const uint4*)&kr[nn];
      uint4 c = *(const uint4*)&vr[nn];
      const unsigned short* pa = (const unsigned short*)&a;
      const unsigned short* pc = (const unsigned short*)&c;
#pragma unroll
      for (int jj = 0; jj < 8; ++jj) { sk_ += b2f(pa[jj]); sv_ += b2f(pc[jj]); }
    }
    mkp[wave][lane] = sk_;
    mvp[wave][lane] = sv_;
  }
  __syncthreads();

  const int r = tid >> 2;
  const int c0 = (tid & 3) * 16;
  if (tid < 64) {
    mks[tid] = (mkp[0][tid] + mkp[1][tid] + mkp[2][tid] + mkp[3][tid]) * invN;
    mvs[tid] = (mvp[0][tid] + mvp[1][tid] + mvp[2][tid] + mvp[3][tid]) * invN;
    bs[tid] = 0.f;
  }
#pragma unroll
  for (int c = 0; c < 16; ++c) Ws[r][c0 + c] = 0.f;
  __syncthreads();

  // 4 GD iterations:  Wn = W + P - G*W - mk (x) b ;  bn = mv - mk*W
  for (int it = 0; it < 4; ++it) {
    float wn[16];
#pragma unroll
    for (int c = 0; c < 16; ++c)
      wn[c] = Ws[r][c0 + c] + Ps[r][c0 + c] - mks[r] * bs[c0 + c];
    for (int j = 0; j < 64; ++j) {
      float g = Gs[r][j];
#pragma unroll
      for (int c = 0; c < 16; ++c) wn[c] -= g * Ws[j][c0 + c];
    }
    float bn = 0.f;
    if (tid < 64) {
      bn = mvs[tid];
      for (int j = 0; j < 64; ++j) bn -= mks[j] * Ws[j][tid];
    }
    __syncthreads();
#pragma unroll
    for (int c = 0; c < 16; ++c) Ws[r][c0 + c] = wn[c];
    if (tid < 64) bs[tid] = bn;
    __syncthreads();
  }

  // emit W^T as bf16 (Wtb[bh][dd][j] = W[j][dd]) and b as fp32
  unsigned short* wout = Wtb + (size_t)bh * HDIM * HDIM;
#pragma unroll
  for (int c = 0; c < 16; ++c)
    wout[(size_t)(c0 + c) * HDIM + r] = f2b(Ws[r][c0 + c]);
  if (tid < 64) bvec[(size_t)bh * HDIM + tid] = bs[tid];
}

// ------------- attn[m][h*64+dd] = sum_j q[m][j] W[j][dd] + b[dd] (bf16 out) -------------
__global__ __launch_bounds__(256) void attn_qw(const unsigned short* __restrict__ qkvb,
                                               const unsigned short* __restrict__ Wtb,
                                               const float* __restrict__ bvec,
                                               unsigned short* __restrict__ attnb) {
  const int h = blockIdx.y;
  const int m0 = blockIdx.x * 128;
  const int bh = ((m0 >> 10) << 4) + h;
  const int tid = threadIdx.x;
  const int lane = tid & 63, wave = tid >> 6;
  const int frow = lane & 15;
  const int fk = (lane >> 4) * 8;

  f32x4 acc[2][4];
#pragma unroll
  for (int j = 0; j < 4; ++j) {
    float bv = bvec[(size_t)bh * HDIM + j * 16 + frow];
    f32x4 t; t[0] = bv; t[1] = bv; t[2] = bv; t[3] = bv;
    acc[0][j] = t; acc[1][j] = t;
  }

  const unsigned short* qbase = qkvb + (size_t)(m0 + wave * 32) * NQKV + h * HDIM;
  const unsigned short* wbase = Wtb + (size_t)bh * HDIM * HDIM;
#pragma unroll
  for (int s = 0; s < 2; ++s) {
    bf16x8 af[2], wf[4];
#pragma unroll
    for (int i = 0; i < 2; ++i)
      af[i] = *(const bf16x8*)&qbase[(size_t)(i * 16 + frow) * NQKV + s * 32 + fk];
#pragma unroll
    for (int j = 0; j < 4; ++j)
      wf[j] = *(const bf16x8*)&wbase[(size_t)(j * 16 + frow) * HDIM + s * 32 + fk];
#pragma unroll
    for (int i = 0; i < 2; ++i)
#pragma unroll
      for (int j = 0; j < 4; ++j)
        acc[i][j] = __builtin_amdgcn_mfma_f32_16x16x32_bf16(af[i], wf[j], acc[i][j], 0, 0, 0);
  }

  const int orow = m0 + wave * 32 + (lane >> 4) * 4;
#pragma unroll
  for (int i = 0; i < 2; ++i)
#pragma unroll
    for (int j = 0; j < 4; ++j)
#pragma unroll
      for (int rr = 0; rr < 4; ++rr)
        attnb[(size_t)(orow + i * 16 + rr) * DIMC + h * HDIM + j * 16 + frow] = f2b(acc[i][j][rr]);
}

extern "C" void kernel_launch(void* const* d_in, const int* in_sizes, int n_in,
                              void* d_out, int out_size, void* d_ws, size_t ws_size,
                              hipStream_t stream) {
  const float* x      = (const float*)d_in[0];
  const float* w_qkv  = (const float*)d_in[1];
  const float* w_proj = (const float*)d_in[2];
  const float* b_proj = (const float*)d_in[3];

  // workspace layout (bytes)
  char* ws = (char*)d_ws;
  unsigned short* xb    = (unsigned short*)(ws + 0);          //  16,777,216
  unsigned short* wqT   = (unsigned short*)(ws + 16777216);   //   6,291,456
  unsigned short* wpT   = (unsigned short*)(ws + 23068672);   //   2,097,152
  unsigned short* qkvb  = (unsigned short*)(ws + 25165824);   //  50,331,648
  unsigned short* kt    = (unsigned short*)(ws + 75497472);   //  16,777,216
  unsigned short* vt    = (unsigned short*)(ws + 92274688);   //  16,777,216
  unsigned short* attnb = (unsigned short*)(ws + 109051904);  //  16,777,216
  unsigned short* Wtb   = (unsigned short*)(ws + 125829120);  //   1,048,576
  float*          bvec  = (float*)(ws + 126877696);           //      32,768
  if (ws_size < (size_t)126910464) return;  // clean fail if workspace too small

  // allow 128 KiB dynamic LDS for the slab-pipelined GEMMs (idempotent, host-side)
  hipFuncSetAttribute((const void*)gemm8<256, 0>,
                      hipFuncAttributeMaxDynamicSharedMemorySize, 131072);
  hipFuncSetAttribute((const void*)gemm8<128, 1>,
                      hipFuncAttributeMaxDynamicSharedMemorySize, 131072);

  cvt_bf16<<<8192, 256, 0, stream>>>(x, xb, MROWS * DIMC / 4);
  transpose_cvt<<<dim3(96, 32), dim3(32, 8), 0, stream>>>(w_qkv, wqT, 1024, 3072);
  transpose_cvt<<<dim3(32, 32), dim3(32, 8), 0, stream>>>(w_proj, wpT, 1024, 1024);
  // qkv = xb @ wqT^T : M=8192, N=3072, 256x256 tiles -> 32*12 = 384 blocks
  gemm8<256, 0><<<dim3(384), dim3(512), 131072, stream>>>(xb, wqT, qkvb, nullptr, NQKV, 12);
  transpose_kv<<<dim3(16, 128, 2), 256, 0, stream>>>(qkvb, kt, vt);
  stats_gd<<<128, 256, 0, stream>>>(kt, vt, Wtb, bvec);
  attn_qw<<<dim3(64, 16), 256, 0, stream>>>(qkvb, Wtb, bvec, attnb);
  // out = attnb @ wpT^T + b : M=8192, N=1024, 128x256 tiles -> 64*4 = 256 blocks
  gemm8<128, 1><<<dim3(256), dim3(512), 98304, stream>>>(attnb, wpT, d_out, b_proj, DIMC, 4);
}

// Round 3
// 197.970 us; speedup vs baseline: 1.0735x; 1.0116x over previous
//
#include <hip/hip_runtime.h>

// MTTT attention, MI355X gfx950.
// B=8, N=1024, C=1024, H=16, d=64, INNER_ITR=4, INNER_LR=1.0
//
// Algebra: the inner GD loop only needs G=k^Tk/N, P=k^Tv/N, mk, mv:
//   W <- W + P - G*W - mk (x) b ;  b <- mv - mk*W   (old W,b on RHS)
// which is an exact rearrangement of the reference iteration.

#define SEQ    1024
#define NBATCH 8
#define DIMC   1024
#define NHEAD  16
#define HDIM   64
#define MROWS  8192      // NBATCH*SEQ
#define NQKV   3072

typedef __attribute__((ext_vector_type(8))) __bf16 bf16x8;
typedef __attribute__((ext_vector_type(4))) float  f32x4;

__device__ __forceinline__ unsigned short f2b(float f) {
  union { float f; unsigned int u; } v; v.f = f;
  unsigned int r = (v.u + 0x7FFFu + ((v.u >> 16) & 1u)) >> 16; // RNE
  return (unsigned short)r;
}
__device__ __forceinline__ float b2f(unsigned short u) {
  union { unsigned int u; float f; } v; v.u = ((unsigned int)u) << 16;
  return v.f;
}

// async global->LDS, 16B per lane; LDS dest = wave-uniform base + lane*16
__device__ __forceinline__ void load_lds16(const void* g, void* l) {
  __builtin_amdgcn_global_load_lds(
      (__attribute__((address_space(1))) void*)(void*)(g),
      (__attribute__((address_space(3))) void*)(l), 16, 0, 0);
}

#define FENCE asm volatile("" ::: "memory")
#define BAR   __builtin_amdgcn_s_barrier()
#define LGKM0 do { asm volatile("s_waitcnt lgkmcnt(0)" ::: "memory"); \
                   __builtin_amdgcn_sched_barrier(0); } while (0)
#define PRIO1 __builtin_amdgcn_s_setprio(1)
#define PRIO0 __builtin_amdgcn_s_setprio(0)

#define WAITVM(n_) do {                                                    \
    if ((n_) == 0) asm volatile("s_waitcnt vmcnt(0)" ::: "memory");        \
    else if ((n_) == 4) asm volatile("s_waitcnt vmcnt(4)" ::: "memory");   \
    else if ((n_) == 6) asm volatile("s_waitcnt vmcnt(6)" ::: "memory");   \
    else asm volatile("s_waitcnt vmcnt(8)" ::: "memory");                  \
  } while (0)

// ---------------- fp32 -> bf16 convert (vectorized) ----------------
__global__ __launch_bounds__(256) void cvt_bf16(const float* __restrict__ in,
                                                unsigned short* __restrict__ out,
                                                int n4) {
  int i = blockIdx.x * 256 + threadIdx.x;
  if (i >= n4) return;
  float4 v = ((const float4*)in)[i];
  ushort4 o;
  o.x = f2b(v.x); o.y = f2b(v.y); o.z = f2b(v.z); o.w = f2b(v.w);
  ((ushort4*)out)[i] = o;
}

// ------------- fp32 (R x Cc) -> bf16 transposed (Cc x R) -------------
__global__ __launch_bounds__(256) void transpose_cvt(const float* __restrict__ in,
                                                     unsigned short* __restrict__ out,
                                                     int R, int Cc) {
  __shared__ unsigned short tile[32][33];
  int c0 = blockIdx.x * 32, r0 = blockIdx.y * 32;
  int tx = threadIdx.x, ty = threadIdx.y;
  for (int i = ty; i < 32; i += 8)
    tile[i][tx] = f2b(in[(size_t)(r0 + i) * Cc + c0 + tx]);
  __syncthreads();
  for (int i = ty; i < 32; i += 8)
    out[(size_t)(c0 + i) * R + r0 + tx] = tile[tx][i];
}

// =====================================================================
// 8-phase slab-pipelined NT bf16 GEMM (m201 port), K fixed at 1024.
//   C[m][n] = sum_k A[m][k] * BT[n][k]  (+bias, fp32 out, if STORE_F32)
// Tile BM x 256, K-tile 64, 8 waves (2Mx4N), wave tile (BM/2) x 64.
// Double-buffered K-tiles; 8 phases per 2 K-tiles; per phase:
//   {ds_read quadrant frags || stage 1 half-tile} -> barrier ->
//   lgkmcnt(0)+sched_barrier -> setprio(1) MFMA quadrant setprio(0)
//   [-> counted vmcnt at P4/P8] -> barrier
// LDS rows are 128B; T2 swizzle: 16B chunk c stored at c ^ (row&7);
// global source pre-swizzled (linear global_load_lds dest), read-side
// XOR is a per-lane constant since all frag base rows are x16.
// MFMA operands swapped (mfma(B,A)): thread's 4 acc regs = 4
// consecutive output COLUMNS -> packed ushort4/float4 stores.
// =====================================================================
template <int BM, int STORE_F32>
__global__ __launch_bounds__(512, 2) void gemm_p8(const unsigned short* __restrict__ A,
                                                  const unsigned short* __restrict__ BT,
                                                  void* __restrict__ Cout,
                                                  const float* __restrict__ bias,
                                                  int N, int NBN) {
  constexpr int MI = BM / 32;          // m-frags per wave
  constexpr int MH = MI / 2;           // m-frags per quadrant
  constexpr int ABYTES = BM * 128;     // A K-tile bytes (BM x 64 x bf16)
  constexpr int BBYTES = 32768;        // B K-tile bytes (256 x 64 x bf16)
  constexpr int BUFB = ABYTES + BBYTES;
  constexpr int ACALLS = BM / 128;     // gload_lds calls per A half-tile
  constexpr int NTC = 4 + 2 * ACALLS;  // gload_lds calls per K-tile

  extern __shared__ __align__(16) char ldsb[];

  const int tid = threadIdx.x;
  const int lane = tid & 63, wave = tid >> 6;
  const int wr = wave >> 2, wc = wave & 3;
  const int frow = lane & 15;
  const int g4 = lane >> 4;
  const int cz0 = (g4 ^ (lane & 7)) * 16;        // kk=0 swizzled chunk byte
  const int cz1 = ((4 | g4) ^ (lane & 7)) * 16;  // kk=1

  // XCD-aware bijective block swizzle (gridDim.x % 8 == 0)
  const int cpx = gridDim.x >> 3;
  const int wg = (blockIdx.x & 7) * cpx + (blockIdx.x >> 3);
  const int bm = wg / NBN, bn = wg % NBN;
  const size_t m0 = (size_t)bm * BM, n0 = (size_t)bn * 256;

  // staging source: thread t covers LDS (row = call*64 + (t>>3), chunk = t&7)
  // which must hold global 16B-chunk (t&7) ^ (row&7) = (t&7) ^ ((t>>3)&7)
  const int srow = tid >> 3;
  const int scol = ((tid & 7) ^ ((tid >> 3) & 7)) * 8;  // element offset
  const unsigned short* srcA = A + (m0 + srow) * 1024 + scol;
  const unsigned short* srcB = BT + (n0 + srow) * 1024 + scol;

  const int aBase = (wr * (BM / 2) + frow) * 128;
  const int bBase = (wc * 64 + frow) * 128;

  f32x4 acc[MI][4];
  if (STORE_F32) {
#pragma unroll
    for (int j = 0; j < 4; ++j) {
      float4 bv = *(const float4*)&bias[n0 + wc * 64 + j * 16 + g4 * 4];
      f32x4 t; t[0] = bv.x; t[1] = bv.y; t[2] = bv.z; t[3] = bv.w;
#pragma unroll
      for (int i = 0; i < MI; ++i) acc[i][j] = t;
    }
  } else {
#pragma unroll
    for (int i = 0; i < MI; ++i)
#pragma unroll
      for (int j = 0; j < 4; ++j) acc[i][j] = f32x4{0.f, 0.f, 0.f, 0.f};
  }

  auto stageA = [&](int buf_, int h_, int tt_) {
    char* dst = ldsb + buf_ * BUFB + h_ * (ABYTES / 2) + wave * 1024;
    const unsigned short* s = srcA + (size_t)(h_ * (BM / 2)) * 1024 + tt_ * 64;
    load_lds16(s, dst);
    if constexpr (ACALLS == 2) load_lds16(s + 65536, dst + 8192);
  };
  auto stageB = [&](int buf_, int h_, int tt_) {
    char* dst = ldsb + buf_ * BUFB + ABYTES + h_ * 16384 + wave * 1024;
    const unsigned short* s = srcB + (size_t)(h_ * 128) * 1024 + tt_ * 64;
    load_lds16(s, dst);
    load_lds16(s + 65536, dst + 8192);
  };

#define READ_A(buf_, mh_, dst_) do {                                     \
    const char* ab_ = ldsb + (buf_) * BUFB + aBase + (mh_) * (MH * 2048);\
    _Pragma("unroll") for (int fi = 0; fi < MH; ++fi) {                  \
      dst_[fi][0] = *(const bf16x8*)(ab_ + fi * 2048 + cz0);             \
      dst_[fi][1] = *(const bf16x8*)(ab_ + fi * 2048 + cz1); }           \
  } while (0)

#define READ_B(buf_, nh_, dst_) do {                                     \
    const char* bb_ = ldsb + (buf_) * BUFB + ABYTES + bBase + (nh_) * 4096;\
    _Pragma("unroll") for (int fj = 0; fj < 2; ++fj) {                   \
      dst_[fj][0] = *(const bf16x8*)(bb_ + fj * 2048 + cz0);             \
      dst_[fj][1] = *(const bf16x8*)(bb_ + fj * 2048 + cz1); }           \
  } while (0)

#define MFMAQ(mh_, nh_, bb_)                                             \
    _Pragma("unroll") for (int fi = 0; fi < MH; ++fi)                    \
    _Pragma("unroll") for (int fj = 0; fj < 2; ++fj)                     \
    _Pragma("unroll") for (int kk = 0; kk < 2; ++kk)                     \
      acc[(mh_) * MH + fi][(nh_) * 2 + fj] =                             \
        __builtin_amdgcn_mfma_f32_16x16x32_bf16(bb_[fj][kk], aq[fi][kk], \
            acc[(mh_) * MH + fi][(nh_) * 2 + fj], 0, 0, 0)

  // prologue: stage K-tiles 0 (buf0) and 1 (buf1) fully
  stageB(0, 0, 0); stageB(0, 1, 0); stageA(0, 0, 0); stageA(0, 1, 0);
  stageB(1, 0, 1); stageB(1, 1, 1); stageA(1, 0, 1); stageA(1, 1, 1);
  WAITVM(NTC);   // drain tile 0 (tile 1 stays in flight)
  FENCE; BAR;

  // 16 K-tiles; iteration = 2 K-tiles = 8 phases; last iteration peeled via st
#pragma unroll 1
  for (int it = 0; it < 8; ++it) {
    const int st = (it < 7);
    const int t2 = 2 * it + 2, t3 = 2 * it + 3;
    bf16x8 aq[MH][2], b0[2][2], b1[2][2];
    // ---- K-tile 2it (buf0) ----
    // P1: read A(mh0), B(nh0)
    READ_A(0, 0, aq); READ_B(0, 0, b0);
    FENCE; BAR; LGKM0;
    PRIO1; MFMAQ(0, 0, b0); PRIO0; FENCE; BAR;
    // P2: read B(nh1)
    READ_B(0, 1, b1);
    FENCE; BAR; LGKM0;
    PRIO1; MFMAQ(0, 1, b1); PRIO0; FENCE; BAR;
    // P3: read A(mh1); stage (t+2).B0 (buf0 B rows free after P2)
    READ_A(0, 1, aq);
    if (st) stageB(0, 0, t2);
    FENCE; BAR; LGKM0;
    PRIO1; MFMAQ(1, 0, b0); PRIO0; FENCE; BAR;
    // P4: no reads; stage (t+2).B1; counted vmcnt guards P5 reads of buf1
    if (st) stageB(0, 1, t2);
    FENCE; BAR; LGKM0;
    PRIO1; MFMAQ(1, 1, b1); PRIO0;
    if (st) WAITVM(4); else WAITVM(0);
    FENCE; BAR;
    // ---- K-tile 2it+1 (buf1) ----
    // P5: read A(mh0), B(nh0); stage (t+2).A0 (buf0 A free after P3)
    READ_A(1, 0, aq); READ_B(1, 0, b0);
    if (st) stageA(0, 0, t2);
    FENCE; BAR; LGKM0;
    PRIO1; MFMAQ(0, 0, b0); PRIO0; FENCE; BAR;
    // P6: read B(nh1); stage (t+2).A1
    READ_B(1, 1, b1);
    if (st) stageA(0, 1, t2);
    FENCE; BAR; LGKM0;
    PRIO1; MFMAQ(0, 1, b1); PRIO0; FENCE; BAR;
    // P7: read A(mh1); stage (t+3).B0 (buf1 B rows free after P6)
    READ_A(1, 1, aq);
    if (st) stageB(1, 0, t3);
    FENCE; BAR; LGKM0;
    PRIO1; MFMAQ(1, 0, b0); PRIO0; FENCE; BAR;
    // P8: stage (t+3).B1, A0, A1 (buf1 A free after P7); vmcnt guards next P1
    if (st) { stageB(1, 1, t3); stageA(1, 0, t3); stageA(1, 1, t3); }
    FENCE; BAR; LGKM0;
    PRIO1; MFMAQ(1, 1, b1); PRIO0;
    WAITVM(NTC);   // drains tile t+2 (no-op on final iteration)
    FENCE; BAR;
  }
#undef READ_A
#undef READ_B
#undef MFMAQ

  // epilogue: thread holds 4 consecutive output columns per acc frag
  const size_t mbase = m0 + wr * (BM / 2) + frow;
  const size_t nbase = n0 + wc * 64 + g4 * 4;
  if (STORE_F32) {
    float* C = (float*)Cout;
#pragma unroll
    for (int i = 0; i < MI; ++i)
#pragma unroll
      for (int j = 0; j < 4; ++j) {
        float4 o; o.x = acc[i][j][0]; o.y = acc[i][j][1];
        o.z = acc[i][j][2]; o.w = acc[i][j][3];
        *(float4*)&C[(mbase + i * 16) * N + nbase + j * 16] = o;
      }
  } else {
    unsigned short* C = (unsigned short*)Cout;
#pragma unroll
    for (int i = 0; i < MI; ++i)
#pragma unroll
      for (int j = 0; j < 4; ++j) {
        ushort4 o; o.x = f2b(acc[i][j][0]); o.y = f2b(acc[i][j][1]);
        o.z = f2b(acc[i][j][2]); o.w = f2b(acc[i][j][3]);
        *(ushort4*)&C[(mbase + i * 16) * N + nbase + j * 16] = o;
      }
  }
}

// ------------- k,v: qkv layout (m, 3C) -> per-head d-major [bh][d][N] -------------
__global__ __launch_bounds__(256) void transpose_kv(const unsigned short* __restrict__ qkvb,
                                                    unsigned short* __restrict__ kt,
                                                    unsigned short* __restrict__ vt) {
  __shared__ unsigned short tile[64][80];  // stride 160B: 16B-aligned rows
  const int nc = blockIdx.x * 64;
  const int bh = blockIdx.y;
  const int which = blockIdx.z;           // 0 -> k (col base C), 1 -> v (col base 2C)
  const int b = bh >> 4, h = bh & 15;
  const int tid = threadIdx.x;
  const unsigned short* src = qkvb + (size_t)(b * SEQ + nc) * NQKV + (which + 1) * DIMC + h * HDIM;
  for (int idx = tid; idx < 512; idx += 256) {
    int rr = idx >> 3, ss = (idx & 7) * 8;
    *(uint4*)&tile[rr][ss] = *(const uint4*)&src[(size_t)rr * NQKV + ss];
  }
  __syncthreads();
  unsigned short* dst = (which ? vt : kt) + (size_t)bh * HDIM * SEQ;
  for (int idx = tid; idx < 512; idx += 256) {
    int dd = idx >> 3, ns = (idx & 7) * 8;
    alignas(16) unsigned short tmp[8];
#pragma unroll
    for (int jj = 0; jj < 8; ++jj) tmp[jj] = tile[ns + jj][dd];
    *(uint4*)&dst[(size_t)dd * SEQ + nc + ns] = *(const uint4*)tmp;
  }
}

// ------------- per-(b,h): G,P via MFMA + mk,mv + 4 GD iters -> W^T (bf16), b -------------
__global__ __launch_bounds__(256) void stats_gd(const unsigned short* __restrict__ kt,
                                                const unsigned short* __restrict__ vt,
                                                unsigned short* __restrict__ Wtb,
                                                float* __restrict__ bvec) {
  __shared__ float Gs[64][68];
  __shared__ float Ps[64][68];
  __shared__ float Ws[64][68];
  __shared__ float mkp[4][64], mvp[4][64];
  __shared__ float mks[64], mvs[64], bs[64];

  const int bh = blockIdx.x;
  const int tid = threadIdx.x;
  const int lane = tid & 63, wave = tid >> 6;
  const unsigned short* kb = kt + (size_t)bh * HDIM * SEQ;
  const unsigned short* vb = vt + (size_t)bh * HDIM * SEQ;
  const int frow = lane & 15;
  const int fk = (lane >> 4) * 8;

  // G[i][j] = sum_n ktd[i][n]*ktd[j][n]; both operand frags read kt rows identically.
  f32x4 accG[4], accP[4];
#pragma unroll
  for (int j = 0; j < 4; ++j) {
    accG[j] = f32x4{0.f, 0.f, 0.f, 0.f};
    accP[j] = f32x4{0.f, 0.f, 0.f, 0.f};
  }
  for (int nb = 0; nb < SEQ; nb += 32) {
    bf16x8 af = *(const bf16x8*)&kb[(size_t)(wave * 16 + frow) * SEQ + nb + fk];  // i-tile = wave
    bf16x8 kf[4], vf[4];
#pragma unroll
    for (int j = 0; j < 4; ++j)
      kf[j] = *(const bf16x8*)&kb[(size_t)(j * 16 + frow) * SEQ + nb + fk];
#pragma unroll
    for (int j = 0; j < 4; ++j)
      vf[j] = *(const bf16x8*)&vb[(size_t)(j * 16 + frow) * SEQ + nb + fk];
#pragma unroll
    for (int j = 0; j < 4; ++j) {
      accG[j] = __builtin_amdgcn_mfma_f32_16x16x32_bf16(af, kf[j], accG[j], 0, 0, 0);
      accP[j] = __builtin_amdgcn_mfma_f32_16x16x32_bf16(af, vf[j], accP[j], 0, 0, 0);
    }
  }
  const float invN = 1.0f / (float)SEQ;
  const int orow = wave * 16 + (lane >> 4) * 4;
#pragma unroll
  for (int j = 0; j < 4; ++j)
#pragma unroll
    for (int r = 0; r < 4; ++r) {
      Gs[orow + r][j * 16 + frow] = accG[j][r] * invN;
      Ps[orow + r][j * 16 + frow] = accP[j][r] * invN;
    }

  // row means: thread (wave,lane): quarter-sums of row `lane`
  {
    float sk_ = 0.f, sv_ = 0.f;
    const unsigned short* kr = &kb[(size_t)lane * SEQ + wave * 256];
    const unsigned short* vr = &vb[(size_t)lane * SEQ + wave * 256];
    for (int nn = 0; nn < 256; nn += 8) {
      uint4 a = *(const uint4*)&kr[nn];
      uint4 c = *(const uint4*)&vr[nn];
      const unsigned short* pa = (const unsigned short*)&a;
      const unsigned short* pc = (const unsigned short*)&c;
#pragma unroll
      for (int jj = 0; jj < 8; ++jj) { sk_ += b2f(pa[jj]); sv_ += b2f(pc[jj]); }
    }
    mkp[wave][lane] = sk_;
    mvp[wave][lane] = sv_;
  }
  __syncthreads();

  const int r = tid >> 2;
  const int c0 = (tid & 3) * 16;
  if (tid < 64) {
    mks[tid] = (mkp[0][tid] + mkp[1][tid] + mkp[2][tid] + mkp[3][tid]) * invN;
    mvs[tid] = (mvp[0][tid] + mvp[1][tid] + mvp[2][tid] + mvp[3][tid]) * invN;
    bs[tid] = 0.f;
  }
#pragma unroll
  for (int c = 0; c < 16; ++c) Ws[r][c0 + c] = 0.f;
  __syncthreads();

  // 4 GD iterations:  Wn = W + P - G*W - mk (x) b ;  bn = mv - mk*W
  for (int it = 0; it < 4; ++it) {
    float wn[16];
#pragma unroll
    for (int c = 0; c < 16; ++c)
      wn[c] = Ws[r][c0 + c] + Ps[r][c0 + c] - mks[r] * bs[c0 + c];
    for (int j = 0; j < 64; ++j) {
      float g = Gs[r][j];
#pragma unroll
      for (int c = 0; c < 16; ++c) wn[c] -= g * Ws[j][c0 + c];
    }
    float bn = 0.f;
    if (tid < 64) {
      bn = mvs[tid];
      for (int j = 0; j < 64; ++j) bn -= mks[j] * Ws[j][tid];
    }
    __syncthreads();
#pragma unroll
    for (int c = 0; c < 16; ++c) Ws[r][c0 + c] = wn[c];
    if (tid < 64) bs[tid] = bn;
    __syncthreads();
  }

  // emit W^T as bf16 (Wtb[bh][dd][j] = W[j][dd]) and b as fp32
  unsigned short* wout = Wtb + (size_t)bh * HDIM * HDIM;
#pragma unroll
  for (int c = 0; c < 16; ++c)
    wout[(size_t)(c0 + c) * HDIM + r] = f2b(Ws[r][c0 + c]);
  if (tid < 64) bvec[(size_t)bh * HDIM + tid] = bs[tid];
}

// ------------- attn[m][h*64+dd] = sum_j q[m][j] W[j][dd] + b[dd] (bf16 out) -------------
__global__ __launch_bounds__(256) void attn_qw(const unsigned short* __restrict__ qkvb,
                                               const unsigned short* __restrict__ Wtb,
                                               const float* __restrict__ bvec,
                                               unsigned short* __restrict__ attnb) {
  const int h = blockIdx.y;
  const int m0 = blockIdx.x * 128;
  const int bh = ((m0 >> 10) << 4) + h;
  const int tid = threadIdx.x;
  const int lane = tid & 63, wave = tid >> 6;
  const int frow = lane & 15;
  const int fk = (lane >> 4) * 8;

  f32x4 acc[2][4];
#pragma unroll
  for (int j = 0; j < 4; ++j) {
    float bv = bvec[(size_t)bh * HDIM + j * 16 + frow];
    f32x4 t; t[0] = bv; t[1] = bv; t[2] = bv; t[3] = bv;
    acc[0][j] = t; acc[1][j] = t;
  }

  const unsigned short* qbase = qkvb + (size_t)(m0 + wave * 32) * NQKV + h * HDIM;
  const unsigned short* wbase = Wtb + (size_t)bh * HDIM * HDIM;
#pragma unroll
  for (int s = 0; s < 2; ++s) {
    bf16x8 af[2], wf[4];
#pragma unroll
    for (int i = 0; i < 2; ++i)
      af[i] = *(const bf16x8*)&qbase[(size_t)(i * 16 + frow) * NQKV + s * 32 + fk];
#pragma unroll
    for (int j = 0; j < 4; ++j)
      wf[j] = *(const bf16x8*)&wbase[(size_t)(j * 16 + frow) * HDIM + s * 32 + fk];
#pragma unroll
    for (int i = 0; i < 2; ++i)
#pragma unroll
      for (int j = 0; j < 4; ++j)
        acc[i][j] = __builtin_amdgcn_mfma_f32_16x16x32_bf16(af[i], wf[j], acc[i][j], 0, 0, 0);
  }

  const int orow = m0 + wave * 32 + (lane >> 4) * 4;
#pragma unroll
  for (int i = 0; i < 2; ++i)
#pragma unroll
    for (int j = 0; j < 4; ++j)
#pragma unroll
      for (int rr = 0; rr < 4; ++rr)
        attnb[(size_t)(orow + i * 16 + rr) * DIMC + h * HDIM + j * 16 + frow] = f2b(acc[i][j][rr]);
}

extern "C" void kernel_launch(void* const* d_in, const int* in_sizes, int n_in,
                              void* d_out, int out_size, void* d_ws, size_t ws_size,
                              hipStream_t stream) {
  const float* x      = (const float*)d_in[0];
  const float* w_qkv  = (const float*)d_in[1];
  const float* w_proj = (const float*)d_in[2];
  const float* b_proj = (const float*)d_in[3];

  // workspace layout (bytes)
  char* ws = (char*)d_ws;
  unsigned short* xb    = (unsigned short*)(ws + 0);          //  16,777,216
  unsigned short* wqT   = (unsigned short*)(ws + 16777216);   //   6,291,456
  unsigned short* wpT   = (unsigned short*)(ws + 23068672);   //   2,097,152
  unsigned short* qkvb  = (unsigned short*)(ws + 25165824);   //  50,331,648
  unsigned short* kt    = (unsigned short*)(ws + 75497472);   //  16,777,216
  unsigned short* vt    = (unsigned short*)(ws + 92274688);   //  16,777,216
  unsigned short* attnb = (unsigned short*)(ws + 109051904);  //  16,777,216
  unsigned short* Wtb   = (unsigned short*)(ws + 125829120);  //   1,048,576
  float*          bvec  = (float*)(ws + 126877696);           //      32,768
  if (ws_size < (size_t)126910464) return;  // clean fail if workspace too small

  // allow up to 128 KiB dynamic LDS for the 8-phase GEMMs (idempotent, host-side)
  hipFuncSetAttribute((const void*)gemm_p8<256, 0>,
                      hipFuncAttributeMaxDynamicSharedMemorySize, 131072);
  hipFuncSetAttribute((const void*)gemm_p8<128, 1>,
                      hipFuncAttributeMaxDynamicSharedMemorySize, 131072);

  cvt_bf16<<<8192, 256, 0, stream>>>(x, xb, MROWS * DIMC / 4);
  transpose_cvt<<<dim3(96, 32), dim3(32, 8), 0, stream>>>(w_qkv, wqT, 1024, 3072);
  transpose_cvt<<<dim3(32, 32), dim3(32, 8), 0, stream>>>(w_proj, wpT, 1024, 1024);
  // qkv = xb @ wqT^T : M=8192, N=3072 -> 32*12 = 384 blocks (256x256 tiles)
  gemm_p8<256, 0><<<dim3(384), dim3(512), 131072, stream>>>(xb, wqT, qkvb, nullptr, NQKV, 12);
  transpose_kv<<<dim3(16, 128, 2), 256, 0, stream>>>(qkvb, kt, vt);
  stats_gd<<<128, 256, 0, stream>>>(kt, vt, Wtb, bvec);
  attn_qw<<<dim3(64, 16), 256, 0, stream>>>(qkvb, Wtb, bvec, attnb);
  // out = attnb @ wpT^T + b : M=8192, N=1024 -> 64*4 = 256 blocks (128x256 tiles)
  gemm_p8<128, 1><<<dim3(256), dim3(512), 98304, stream>>>(attnb, wpT, d_out, b_proj, DIMC, 4);
}

// Round 6
// 195.653 us; speedup vs baseline: 1.0862x; 1.0118x over previous
//
#include <hip/hip_runtime.h>

// MTTT attention, MI355X gfx950.
// B=8, N=1024, C=1024, H=16, d=64, INNER_ITR=4, INNER_LR=1.0
//
// Algebra: the inner GD loop only needs G=k^Tk/N, P=k^Tv/N, mk, mv:
//   W <- W + P - G*W - mk (x) b ;  b <- mv - mk*W   (old W,b on RHS)
// which is an exact rearrangement of the reference iteration.

#define SEQ    1024
#define NBATCH 8
#define DIMC   1024
#define NHEAD  16
#define HDIM   64
#define MROWS  8192      // NBATCH*SEQ
#define NQKV   3072

typedef __attribute__((ext_vector_type(8))) __bf16 bf16x8;
typedef __attribute__((ext_vector_type(4))) float  f32x4;

__device__ __forceinline__ unsigned short f2b(float f) {
  union { float f; unsigned int u; } v; v.f = f;
  unsigned int r = (v.u + 0x7FFFu + ((v.u >> 16) & 1u)) >> 16; // RNE
  return (unsigned short)r;
}
__device__ __forceinline__ float b2f(unsigned short u) {
  union { unsigned int u; float f; } v; v.u = ((unsigned int)u) << 16;
  return v.f;
}

// async global->LDS, 16B per lane; LDS dest = wave-uniform base + lane*16
__device__ __forceinline__ void load_lds16(const void* g, void* l) {
  __builtin_amdgcn_global_load_lds(
      (__attribute__((address_space(1))) void*)(void*)(g),
      (__attribute__((address_space(3))) void*)(l), 16, 0, 0);
}

#define FENCE  asm volatile("" ::: "memory")
#define BAR    __builtin_amdgcn_s_barrier()
#define PRIO1  __builtin_amdgcn_s_setprio(1)
#define PRIO0  __builtin_amdgcn_s_setprio(0)
#define SCHED0 __builtin_amdgcn_sched_barrier(0)

// ---------------- fp32 -> bf16 convert (vectorized) ----------------
__global__ __launch_bounds__(256) void cvt_bf16(const float* __restrict__ in,
                                                unsigned short* __restrict__ out,
                                                int n4) {
  int i = blockIdx.x * 256 + threadIdx.x;
  if (i >= n4) return;
  float4 v = ((const float4*)in)[i];
  ushort4 o;
  o.x = f2b(v.x); o.y = f2b(v.y); o.z = f2b(v.z); o.w = f2b(v.w);
  ((ushort4*)out)[i] = o;
}

// ------------- fp32 (R x Cc) -> bf16 transposed (Cc x R) -------------
__global__ __launch_bounds__(256) void transpose_cvt(const float* __restrict__ in,
                                                     unsigned short* __restrict__ out,
                                                     int R, int Cc) {
  __shared__ unsigned short tile[32][33];
  int c0 = blockIdx.x * 32, r0 = blockIdx.y * 32;
  int tx = threadIdx.x, ty = threadIdx.y;
  for (int i = ty; i < 32; i += 8)
    tile[i][tx] = f2b(in[(size_t)(r0 + i) * Cc + c0 + tx]);
  __syncthreads();
  for (int i = ty; i < 32; i += 8)
    out[(size_t)(c0 + i) * R + r0 + tx] = tile[tx][i];
}

// =====================================================================
// Software-pipelined 8-phase NT bf16 GEMM, K fixed at 1024.
//   C[m][n] = sum_k A[m][k] * BT[n][k]  (+bias, fp32 out, if STORE_F32)
// Tile BM x 256, K-tile 64, 8 waves (2Mx4N), wave tile (BM/2) x 64.
// Phase p: {issue ds_reads for phase p+1's operand || issue ONE stage
//           (global_load_lds half-tile) || MFMA quadrant p from regs
//           read at p-1} -> counted vmcnt -> s_barrier.
//
// REGION MODEL (round-4/5 bug, now systematic): wave group wr reads ONLY
// A-half wr at BOTH mh phases; wave wc reads ONLY B-half wc>>1 at both nh
// phases. Hence region read phases:
//   buf0.A:{P7',P2}  buf0.B:{P8',P1}  buf1.A:{P3,P6}  buf1.B:{P4,P5}
// Stage schedule (each stage after region's last read [WAR; barrier
// separation suffices since ds_reads issued pre-barrier complete before
// any post-barrier global-load data can land], and >= N intervening
// calls before first read [RAW via counted vmcnt]):
//   P1:buf1.B1<-t1  P2:buf0.B0<-t2  P3:buf0.A0<-t2  P4:buf0.A1<-t2
//   P5:buf0.B1<-t2  P6:buf1.B0<-t3  P7:buf1.A0<-t3  P8:buf1.A1<-t3
// Verified min intervening-call sums: BM=256 -> 4 (N=4); BM=128 -> 3
// (N=3); prologue (buf0 full + buf1.{B0,A0,A1}; wait vmcnt(6|4)) and
// final iteration (st=0: stages skipped, phase-end waits -> vmcnt(0))
// both re-verified against every region.
// Reads (one phase ahead of consuming MFMA):
//   P1:b0B1->b1 P2:b0A1->aY P3:b1A0->aX P4:b1B0->b0 P5:b1B1->b1
//   P6:b1A1->aY P7:b0A0->aX(t2) P8:b0B0->b0(t2)
// LDS rows 128B, T2 XOR swizzle (chunk c at c ^ (row&7)); global source
// pre-swizzled, linear global_load_lds dest; read-side XOR per-lane const.
// MFMA operands swapped (mfma(B,A)): thread's 4 acc regs = 4 consecutive
// output COLUMNS -> packed ushort4/float4 stores.
// =====================================================================
template <int BM, int STORE_F32>
__global__ __launch_bounds__(512, 2) void gemm_p8(const unsigned short* __restrict__ A,
                                                  const unsigned short* __restrict__ BT,
                                                  void* __restrict__ Cout,
                                                  const float* __restrict__ bias,
                                                  int N, int NBN) {
  constexpr int MI = BM / 32;          // m-frags per wave
  constexpr int MH = MI / 2;           // m-frags per quadrant
  constexpr int ABYTES = BM * 128;     // A K-tile bytes (BM x 64 x bf16)
  constexpr int BUFB = ABYTES + 32768; // + B K-tile (256 x 64 x bf16)
  constexpr int ACALLS = BM / 128;     // gload_lds calls per A half-tile

  extern __shared__ __align__(16) char ldsb[];

  const int tid = threadIdx.x;
  const int lane = tid & 63, wave = tid >> 6;
  const int wr = wave >> 2, wc = wave & 3;
  const int frow = lane & 15;
  const int g4 = lane >> 4;
  const int cz0 = (g4 ^ (lane & 7)) * 16;        // kk=0 swizzled chunk byte
  const int cz1 = ((4 | g4) ^ (lane & 7)) * 16;  // kk=1

  // XCD-aware bijective block swizzle (gridDim.x % 8 == 0)
  const int cpx = gridDim.x >> 3;
  const int wg = (blockIdx.x & 7) * cpx + (blockIdx.x >> 3);
  const int bm = wg / NBN, bn = wg % NBN;
  const size_t m0 = (size_t)bm * BM, n0 = (size_t)bn * 256;

  // staging source: thread t covers LDS (row = call*64 + (t>>3), chunk = t&7)
  // which must hold global 16B-chunk (t&7) ^ (row&7) = (t&7) ^ ((t>>3)&7)
  const int srow = tid >> 3;
  const int scol = ((tid & 7) ^ ((tid >> 3) & 7)) * 8;  // element offset
  const unsigned short* srcA = A + (m0 + srow) * 1024 + scol;
  const unsigned short* srcB = BT + (n0 + srow) * 1024 + scol;

  const int aBase = (wr * (BM / 2) + frow) * 128;
  const int bBase = (wc * 64 + frow) * 128;

  f32x4 acc[MI][4];
  if (STORE_F32) {
#pragma unroll
    for (int j = 0; j < 4; ++j) {
      float4 bv = *(const float4*)&bias[n0 + wc * 64 + j * 16 + g4 * 4];
      f32x4 t; t[0] = bv.x; t[1] = bv.y; t[2] = bv.z; t[3] = bv.w;
#pragma unroll
      for (int i = 0; i < MI; ++i) acc[i][j] = t;
    }
  } else {
#pragma unroll
    for (int i = 0; i < MI; ++i)
#pragma unroll
      for (int j = 0; j < 4; ++j) acc[i][j] = f32x4{0.f, 0.f, 0.f, 0.f};
  }

  auto stageA = [&](int buf_, int h_, int tt_) {
    char* dst = ldsb + buf_ * BUFB + h_ * (ABYTES / 2) + wave * 1024;
    const unsigned short* s = srcA + (size_t)(h_ * (BM / 2)) * 1024 + tt_ * 64;
    load_lds16(s, dst);
    if constexpr (ACALLS == 2) load_lds16(s + 65536, dst + 8192);
  };
  auto stageB = [&](int buf_, int h_, int tt_) {
    char* dst = ldsb + buf_ * BUFB + ABYTES + h_ * 16384 + wave * 1024;
    const unsigned short* s = srcB + (size_t)(h_ * 128) * 1024 + tt_ * 64;
    load_lds16(s, dst);
    load_lds16(s + 65536, dst + 8192);
  };

#define READ_A(buf_, mh_, dst_) do {                                     \
    const char* ab_ = ldsb + (buf_) * BUFB + aBase + (mh_) * (MH * 2048);\
    _Pragma("unroll") for (int fi = 0; fi < MH; ++fi) {                  \
      dst_[fi][0] = *(const bf16x8*)(ab_ + fi * 2048 + cz0);             \
      dst_[fi][1] = *(const bf16x8*)(ab_ + fi * 2048 + cz1); }           \
  } while (0)

#define READ_B(buf_, nh_, dst_) do {                                     \
    const char* bb_ = ldsb + (buf_) * BUFB + ABYTES + bBase + (nh_) * 4096;\
    _Pragma("unroll") for (int fj = 0; fj < 2; ++fj) {                   \
      dst_[fj][0] = *(const bf16x8*)(bb_ + fj * 2048 + cz0);             \
      dst_[fj][1] = *(const bf16x8*)(bb_ + fj * 2048 + cz1); }           \
  } while (0)

#define MFMAQ(mh_, nh_, as_, bs_)                                        \
    _Pragma("unroll") for (int fi = 0; fi < MH; ++fi)                    \
    _Pragma("unroll") for (int fj = 0; fj < 2; ++fj)                     \
    _Pragma("unroll") for (int kk = 0; kk < 2; ++kk)                     \
      acc[(mh_) * MH + fi][(nh_) * 2 + fj] =                             \
        __builtin_amdgcn_mfma_f32_16x16x32_bf16(bs_[fj][kk], as_[fi][kk],\
            acc[(mh_) * MH + fi][(nh_) * 2 + fj], 0, 0, 0)

  // phase-end wait: counted in steady state, full drain in last iteration
#define VMW(st_) do {                                                    \
    if (st_) {                                                           \
      if constexpr (BM == 256)                                           \
        asm volatile("s_waitcnt vmcnt(4)" ::: "memory");                 \
      else                                                               \
        asm volatile("s_waitcnt vmcnt(3)" ::: "memory");                 \
    } else {                                                             \
      asm volatile("s_waitcnt vmcnt(0)" ::: "memory");                   \
    }                                                                    \
  } while (0)

  bf16x8 aX[MH][2], aY[MH][2], b0[2][2], b1[2][2];

  // ---- prologue: buf0 <- tile0 full; buf1 <- tile1 {B0,A0,A1} ----
  // (buf1.B1 is staged in-loop at P1 with t1 data.)
  stageB(0, 0, 0); stageA(0, 0, 0); stageA(0, 1, 0); stageB(0, 1, 0);
  stageB(1, 0, 1); stageA(1, 0, 1); stageA(1, 1, 1);
  if constexpr (BM == 256) asm volatile("s_waitcnt vmcnt(6)" ::: "memory");
  else                     asm volatile("s_waitcnt vmcnt(4)" ::: "memory");
  FENCE; BAR;
  READ_A(0, 0, aX); READ_B(0, 0, b0);
  asm volatile("s_waitcnt lgkmcnt(0)" ::: "memory");
  SCHED0;
  FENCE; BAR;

  // 16 K-tiles; iteration = 2 K-tiles (t0=2it->buf0, t1=2it+1->buf1)
#pragma unroll 1
  for (int it = 0; it < 8; ++it) {
    const int st = (it < 7);
    const int t1 = 2 * it + 1, t2 = 2 * it + 2, t3 = 2 * it + 3;
    // P1: MFMA t0.Q00; read buf0.B1->b1; stage buf1.B1<-t1 (uncond)
    READ_B(0, 1, b1);
    stageB(1, 1, t1);
    SCHED0;
    PRIO1; MFMAQ(0, 0, aX, b0); PRIO0; VMW(st); FENCE; BAR;
    // P2: MFMA t0.Q01; read buf0.A1->aY; stage buf0.B0<-t2
    READ_A(0, 1, aY);
    if (st) stageB(0, 0, t2);
    SCHED0;
    PRIO1; MFMAQ(0, 1, aX, b1); PRIO0; VMW(st); FENCE; BAR;
    // P3: MFMA t0.Q10; read buf1.A0->aX; stage buf0.A0<-t2
    READ_A(1, 0, aX);
    if (st) stageA(0, 0, t2);
    SCHED0;
    PRIO1; MFMAQ(1, 0, aY, b0); PRIO0; VMW(st); FENCE; BAR;
    // P4: MFMA t0.Q11; read buf1.B0->b0; stage buf0.A1<-t2
    READ_B(1, 0, b0);
    if (st) stageA(0, 1, t2);
    SCHED0;
    PRIO1; MFMAQ(1, 1, aY, b1); PRIO0; VMW(st); FENCE; BAR;
    // P5: MFMA t1.Q00; read buf1.B1->b1; stage buf0.B1<-t2
    READ_B(1, 1, b1);
    if (st) stageB(0, 1, t2);
    SCHED0;
    PRIO1; MFMAQ(0, 0, aX, b0); PRIO0; VMW(st); FENCE; BAR;
    // P6: MFMA t1.Q01; read buf1.A1->aY; stage buf1.B0<-t3
    READ_A(1, 1, aY);
    if (st) stageB(1, 0, t3);
    SCHED0;
    PRIO1; MFMAQ(0, 1, aX, b1); PRIO0; VMW(st); FENCE; BAR;
    // P7: MFMA t1.Q10; read buf0.A0->aX (t2); stage buf1.A0<-t3
    if (st) { READ_A(0, 0, aX); stageA(1, 0, t3); }
    SCHED0;
    PRIO1; MFMAQ(1, 0, aY, b0); PRIO0; VMW(st); FENCE; BAR;
    // P8: MFMA t1.Q11; read buf0.B0->b0 (t2); stage buf1.A1<-t3
    if (st) { READ_B(0, 0, b0); stageA(1, 1, t3); }
    SCHED0;
    PRIO1; MFMAQ(1, 1, aY, b1); PRIO0; VMW(st); FENCE; BAR;
  }
#undef READ_A
#undef READ_B
#undef MFMAQ
#undef VMW

  // epilogue: thread holds 4 consecutive output columns per acc frag
  const size_t mbase = m0 + wr * (BM / 2) + frow;
  const size_t nbase = n0 + wc * 64 + g4 * 4;
  if (STORE_F32) {
    float* C = (float*)Cout;
#pragma unroll
    for (int i = 0; i < MI; ++i)
#pragma unroll
      for (int j = 0; j < 4; ++j) {
        float4 o; o.x = acc[i][j][0]; o.y = acc[i][j][1];
        o.z = acc[i][j][2]; o.w = acc[i][j][3];
        *(float4*)&C[(mbase + i * 16) * N + nbase + j * 16] = o;
      }
  } else {
    unsigned short* C = (unsigned short*)Cout;
#pragma unroll
    for (int i = 0; i < MI; ++i)
#pragma unroll
      for (int j = 0; j < 4; ++j) {
        ushort4 o; o.x = f2b(acc[i][j][0]); o.y = f2b(acc[i][j][1]);
        o.z = f2b(acc[i][j][2]); o.w = f2b(acc[i][j][3]);
        *(ushort4*)&C[(mbase + i * 16) * N + nbase + j * 16] = o;
      }
  }
}

// ------------- k,v: qkv layout (m, 3C) -> per-head d-major [bh][d][N] -------------
__global__ __launch_bounds__(256) void transpose_kv(const unsigned short* __restrict__ qkvb,
                                                    unsigned short* __restrict__ kt,
                                                    unsigned short* __restrict__ vt) {
  __shared__ unsigned short tile[64][80];  // stride 160B: 16B-aligned rows
  const int nc = blockIdx.x * 64;
  const int bh = blockIdx.y;
  const int which = blockIdx.z;           // 0 -> k (col base C), 1 -> v (col base 2C)
  const int b = bh >> 4, h = bh & 15;
  const int tid = threadIdx.x;
  const unsigned short* src = qkvb + (size_t)(b * SEQ + nc) * NQKV + (which + 1) * DIMC + h * HDIM;
  for (int idx = tid; idx < 512; idx += 256) {
    int rr = idx >> 3, ss = (idx & 7) * 8;
    *(uint4*)&tile[rr][ss] = *(const uint4*)&src[(size_t)rr * NQKV + ss];
  }
  __syncthreads();
  unsigned short* dst = (which ? vt : kt) + (size_t)bh * HDIM * SEQ;
  for (int idx = tid; idx < 512; idx += 256) {
    int dd = idx >> 3, ns = (idx & 7) * 8;
    alignas(16) unsigned short tmp[8];
#pragma unroll
    for (int jj = 0; jj < 8; ++jj) tmp[jj] = tile[ns + jj][dd];
    *(uint4*)&dst[(size_t)dd * SEQ + nc + ns] = *(const uint4*)tmp;
  }
}

// ------------- per-(b,h): G,P via MFMA + mk,mv + 4 GD iters -> W^T (bf16), b -------------
__global__ __launch_bounds__(256) void stats_gd(const unsigned short* __restrict__ kt,
                                                const unsigned short* __restrict__ vt,
                                                unsigned short* __restrict__ Wtb,
                                                float* __restrict__ bvec) {
  __shared__ float Gs[64][68];
  __shared__ float Ps[64][68];
  __shared__ float Ws[64][68];
  __shared__ float mkp[4][64], mvp[4][64];
  __shared__ float mks[64], mvs[64], bs[64];

  const int bh = blockIdx.x;
  const int tid = threadIdx.x;
  const int lane = tid & 63, wave = tid >> 6;
  const unsigned short* kb = kt + (size_t)bh * HDIM * SEQ;
  const unsigned short* vb = vt + (size_t)bh * HDIM * SEQ;
  const int frow = lane & 15;
  const int fk = (lane >> 4) * 8;

  // G[i][j] = sum_n ktd[i][n]*ktd[j][n]; both operand frags read kt rows identically.
  f32x4 accG[4], accP[4];
#pragma unroll
  for (int j = 0; j < 4; ++j) {
    accG[j] = f32x4{0.f, 0.f, 0.f, 0.f};
    accP[j] = f32x4{0.f, 0.f, 0.f, 0.f};
  }
  for (int nb = 0; nb < SEQ; nb += 32) {
    bf16x8 af = *(const bf16x8*)&kb[(size_t)(wave * 16 + frow) * SEQ + nb + fk];  // i-tile = wave
    bf16x8 kf[4], vf[4];
#pragma unroll
    for (int j = 0; j < 4; ++j)
      kf[j] = *(const bf16x8*)&kb[(size_t)(j * 16 + frow) * SEQ + nb + fk];
#pragma unroll
    for (int j = 0; j < 4; ++j)
      vf[j] = *(const bf16x8*)&vb[(size_t)(j * 16 + frow) * SEQ + nb + fk];
#pragma unroll
    for (int j = 0; j < 4; ++j) {
      accG[j] = __builtin_amdgcn_mfma_f32_16x16x32_bf16(af, kf[j], accG[j], 0, 0, 0);
      accP[j] = __builtin_amdgcn_mfma_f32_16x16x32_bf16(af, vf[j], accP[j], 0, 0, 0);
    }
  }
  const float invN = 1.0f / (float)SEQ;
  const int orow = wave * 16 + (lane >> 4) * 4;
#pragma unroll
  for (int j = 0; j < 4; ++j)
#pragma unroll
    for (int r = 0; r < 4; ++r) {
      Gs[orow + r][j * 16 + frow] = accG[j][r] * invN;
      Ps[orow + r][j * 16 + frow] = accP[j][r] * invN;
    }

  // row means: thread (wave,lane): quarter-sums of row `lane`
  {
    float sk_ = 0.f, sv_ = 0.f;
    const unsigned short* kr = &kb[(size_t)lane * SEQ + wave * 256];
    const unsigned short* vr = &vb[(size_t)lane * SEQ + wave * 256];
    for (int nn = 0; nn < 256; nn += 8) {
      uint4 a = *(const uint4*)&kr[nn];
      uint4 c = *(const uint4*)&vr[nn];
      const unsigned short* pa = (const unsigned short*)&a;
      const unsigned short* pc = (const unsigned short*)&c;
#pragma unroll
      for (int jj = 0; jj < 8; ++jj) { sk_ += b2f(pa[jj]); sv_ += b2f(pc[jj]); }
    }
    mkp[wave][lane] = sk_;
    mvp[wave][lane] = sv_;
  }
  __syncthreads();

  const int r = tid >> 2;
  const int c0 = (tid & 3) * 16;
  if (tid < 64) {
    mks[tid] = (mkp[0][tid] + mkp[1][tid] + mkp[2][tid] + mkp[3][tid]) * invN;
    mvs[tid] = (mvp[0][tid] + mvp[1][tid] + mvp[2][tid] + mvp[3][tid]) * invN;
    bs[tid] = 0.f;
  }
#pragma unroll
  for (int c = 0; c < 16; ++c) Ws[r][c0 + c] = 0.f;
  __syncthreads();

  // 4 GD iterations:  Wn = W + P - G*W - mk (x) b ;  bn = mv - mk*W
  for (int it = 0; it < 4; ++it) {
    float wn[16];
#pragma unroll
    for (int c = 0; c < 16; ++c)
      wn[c] = Ws[r][c0 + c] + Ps[r][c0 + c] - mks[r] * bs[c0 + c];
    for (int j = 0; j < 64; ++j) {
      float g = Gs[r][j];
#pragma unroll
      for (int c = 0; c < 16; ++c) wn[c] -= g * Ws[j][c0 + c];
    }
    float bn = 0.f;
    if (tid < 64) {
      bn = mvs[tid];
      for (int j = 0; j < 64; ++j) bn -= mks[j] * Ws[j][tid];
    }
    __syncthreads();
#pragma unroll
    for (int c = 0; c < 16; ++c) Ws[r][c0 + c] = wn[c];
    if (tid < 64) bs[tid] = bn;
    __syncthreads();
  }

  // emit W^T as bf16 (Wtb[bh][dd][j] = W[j][dd]) and b as fp32
  unsigned short* wout = Wtb + (size_t)bh * HDIM * HDIM;
#pragma unroll
  for (int c = 0; c < 16; ++c)
    wout[(size_t)(c0 + c) * HDIM + r] = f2b(Ws[r][c0 + c]);
  if (tid < 64) bvec[(size_t)bh * HDIM + tid] = bs[tid];
}

// ------------- attn[m][h*64+dd] = sum_j q[m][j] W[j][dd] + b[dd] (bf16 out) -------------
__global__ __launch_bounds__(256) void attn_qw(const unsigned short* __restrict__ qkvb,
                                               const unsigned short* __restrict__ Wtb,
                                               const float* __restrict__ bvec,
                                               unsigned short* __restrict__ attnb) {
  const int h = blockIdx.y;
  const int m0 = blockIdx.x * 128;
  const int bh = ((m0 >> 10) << 4) + h;
  const int tid = threadIdx.x;
  const int lane = tid & 63, wave = tid >> 6;
  const int frow = lane & 15;
  const int fk = (lane >> 4) * 8;

  f32x4 acc[2][4];
#pragma unroll
  for (int j = 0; j < 4; ++j) {
    float bv = bvec[(size_t)bh * HDIM + j * 16 + frow];
    f32x4 t; t[0] = bv; t[1] = bv; t[2] = bv; t[3] = bv;
    acc[0][j] = t; acc[1][j] = t;
  }

  const unsigned short* qbase = qkvb + (size_t)(m0 + wave * 32) * NQKV + h * HDIM;
  const unsigned short* wbase = Wtb + (size_t)bh * HDIM * HDIM;
#pragma unroll
  for (int s = 0; s < 2; ++s) {
    bf16x8 af[2], wf[4];
#pragma unroll
    for (int i = 0; i < 2; ++i)
      af[i] = *(const bf16x8*)&qbase[(size_t)(i * 16 + frow) * NQKV + s * 32 + fk];
#pragma unroll
    for (int j = 0; j < 4; ++j)
      wf[j] = *(const bf16x8*)&wbase[(size_t)(j * 16 + frow) * HDIM + s * 32 + fk];
#pragma unroll
    for (int i = 0; i < 2; ++i)
#pragma unroll
      for (int j = 0; j < 4; ++j)
        acc[i][j] = __builtin_amdgcn_mfma_f32_16x16x32_bf16(af[i], wf[j], acc[i][j], 0, 0, 0);
  }

  const int orow = m0 + wave * 32 + (lane >> 4) * 4;
#pragma unroll
  for (int i = 0; i < 2; ++i)
#pragma unroll
    for (int j = 0; j < 4; ++j)
#pragma unroll
      for (int rr = 0; rr < 4; ++rr)
        attnb[(size_t)(orow + i * 16 + rr) * DIMC + h * HDIM + j * 16 + frow] = f2b(acc[i][j][rr]);
}

extern "C" void kernel_launch(void* const* d_in, const int* in_sizes, int n_in,
                              void* d_out, int out_size, void* d_ws, size_t ws_size,
                              hipStream_t stream) {
  const float* x      = (const float*)d_in[0];
  const float* w_qkv  = (const float*)d_in[1];
  const float* w_proj = (const float*)d_in[2];
  const float* b_proj = (const float*)d_in[3];

  // workspace layout (bytes)
  char* ws = (char*)d_ws;
  unsigned short* xb    = (unsigned short*)(ws + 0);          //  16,777,216
  unsigned short* wqT   = (unsigned short*)(ws + 16777216);   //   6,291,456
  unsigned short* wpT   = (unsigned short*)(ws + 23068672);   //   2,097,152
  unsigned short* qkvb  = (unsigned short*)(ws + 25165824);   //  50,331,648
  unsigned short* kt    = (unsigned short*)(ws + 75497472);   //  16,777,216
  unsigned short* vt    = (unsigned short*)(ws + 92274688);   //  16,777,216
  unsigned short* attnb = (unsigned short*)(ws + 109051904);  //  16,777,216
  unsigned short* Wtb   = (unsigned short*)(ws + 125829120);  //   1,048,576
  float*          bvec  = (float*)(ws + 126877696);           //      32,768
  if (ws_size < (size_t)126910464) return;  // clean fail if workspace too small

  // allow up to 128 KiB dynamic LDS for the 8-phase GEMMs (idempotent, host-side)
  hipFuncSetAttribute((const void*)gemm_p8<256, 0>,
                      hipFuncAttributeMaxDynamicSharedMemorySize, 131072);
  hipFuncSetAttribute((const void*)gemm_p8<128, 1>,
                      hipFuncAttributeMaxDynamicSharedMemorySize, 131072);

  cvt_bf16<<<8192, 256, 0, stream>>>(x, xb, MROWS * DIMC / 4);
  transpose_cvt<<<dim3(96, 32), dim3(32, 8), 0, stream>>>(w_qkv, wqT, 1024, 3072);
  transpose_cvt<<<dim3(32, 32), dim3(32, 8), 0, stream>>>(w_proj, wpT, 1024, 1024);
  // qkv = xb @ wqT^T : M=8192, N=3072 -> 32*12 = 384 blocks (256x256 tiles)
  gemm_p8<256, 0><<<dim3(384), dim3(512), 131072, stream>>>(xb, wqT, qkvb, nullptr, NQKV, 12);
  transpose_kv<<<dim3(16, 128, 2), 256, 0, stream>>>(qkvb, kt, vt);
  stats_gd<<<128, 256, 0, stream>>>(kt, vt, Wtb, bvec);
  attn_qw<<<dim3(64, 16), 256, 0, stream>>>(qkvb, Wtb, bvec, attnb);
  // out = attnb @ wpT^T + b : M=8192, N=1024 -> 64*4 = 256 blocks (128x256 tiles)
  gemm_p8<128, 1><<<dim3(256), dim3(512), 98304, stream>>>(attnb, wpT, d_out, b_proj, DIMC, 4);
}